// Round 5
// baseline (69.648 us; speedup 1.0000x reference)
//
#include <hip/hip_runtime.h>
#include <hip/hip_cooperative_groups.h>

namespace cg = cooperative_groups;

namespace {

// 2-point Gauss-Legendre nodes on [0,1], weights 0.5 each.
constexpr double G1 = 0.21132486540518712;
constexpr double G2 = 0.78867513459481288;

__host__ __device__ constexpr double qd(int j, double t) {
    if (j == 0) return 1.0/6.0 - 0.5*t + 0.5*t*t - t*t*t/6.0;
    if (j == 1) return 2.0/3.0 - t*t + 0.5*t*t*t;
    if (j == 2) return 1.0/6.0 + 0.5*t + 0.5*t*t - 0.5*t*t*t;
    return t*t*t/6.0;
}
__host__ __device__ constexpr double qpd(int j, double t) {
    if (j == 0) return -0.5 + t - 0.5*t*t;
    if (j == 1) return -2.0*t + 1.5*t*t;
    if (j == 2) return  0.5 + t - 1.5*t*t;
    return 0.5*t*t;
}
__host__ __device__ constexpr float QG(int j, int g) { return (float)qd (j, g ? G2 : G1); }
__host__ __device__ constexpr float QP(int j, int g) { return (float)qpd(j, g ? G2 : G1); }
// Exact reference polyline basis at t = k/10 (boundary rows only).
__host__ __device__ constexpr float Q(int j, int k)  { return (float)qd(j, k * 0.1); }
__host__ __device__ constexpr float DQ(int j, int s) { return (float)(qd(j, (s + 1) * 0.1) - qd(j, s * 0.1)); }

constexpr int BLOCK = 256;
constexpr int GRID  = 1024;   // 4 blocks/CU on 256 CUs — co-resident for grid.sync()

// 0.5/(1 + 0.01*zs) via 2-term series (e in [0,0.01], |rel err| < 1.1e-6).
__device__ inline float slo_half(float zs) {
    return __fmaf_rn(zs, __fmaf_rn(zs, 5e-5f, -5e-3f), 0.5f);
}

// Exact reference polyline for one clamped row (boundaries only).
__device__ float row_contrib(const float* __restrict__ y, int i, int nknots) {
    const int i0 = max(i - 2, 0), i1 = max(i - 1, 0);
    const int i2 = min(i, nknots), i3 = min(i + 1, nknots);
    const float x0 = y[2 * i0], z0 = y[2 * i0 + 1];
    const float x1 = y[2 * i1], z1 = y[2 * i1 + 1];
    const float x2 = y[2 * i2], z2 = y[2 * i2 + 1];
    const float x3 = y[2 * i3], z3 = y[2 * i3 + 1];

    float zs[11], rch[11];
    #pragma unroll
    for (int k = 0; k < 11; ++k) {
        float v = z0 * Q(0, k);
        v = __fmaf_rn(z1, Q(1, k), v);
        v = __fmaf_rn(z2, Q(2, k), v);
        v = __fmaf_rn(z3, Q(3, k), v);
        zs[k]  = v;
        rch[k] = slo_half(v);
    }
    const float d10 = x1 - x0, d20 = x2 - x0, d30 = x3 - x0;
    float acc = 0.0f;
    #pragma unroll
    for (int s = 0; s < 10; ++s) {
        float dx = d10 * DQ(1, s);
        dx = __fmaf_rn(d20, DQ(2, s), dx);
        dx = __fmaf_rn(d30, DQ(3, s), dx);
        const float dz = zs[s + 1] - zs[s];
        const float dist = __builtin_amdgcn_sqrtf(__fmaf_rn(dx, dx, dz * dz));
        acc = __fmaf_rn(rch[s] + rch[s + 1], dist, acc);
    }
    return acc;
}

__global__ __launch_bounds__(BLOCK) void raybend_coop(
    const float2* __restrict__ y2, int n_interior, int nknots,
    float* __restrict__ partial, float* __restrict__ out) {
    float acc = 0.0f;

    // Grid-stride over interior rows (row = i + 2), 2-pt Gauss per row.
    const int stride = GRID * BLOCK;
    for (int i = blockIdx.x * BLOCK + threadIdx.x; i < n_interior; i += stride) {
        const int r = i + 2;
        const float2 p0 = y2[r - 2];
        const float2 p1 = y2[r - 1];
        const float2 p2 = y2[r];
        const float2 p3 = y2[r + 1];

        const float d10 = p1.x - p0.x, d20 = p2.x - p0.x, d30 = p3.x - p0.x;
        const float e10 = p1.y - p0.y, e20 = p2.y - p0.y, e30 = p3.y - p0.y;

        #pragma unroll
        for (int g = 0; g < 2; ++g) {
            float xp = d10 * QP(1, g);
            xp = __fmaf_rn(d20, QP(2, g), xp);
            xp = __fmaf_rn(d30, QP(3, g), xp);
            float zp = e10 * QP(1, g);
            zp = __fmaf_rn(e20, QP(2, g), zp);
            zp = __fmaf_rn(e30, QP(3, g), zp);
            float zs = p0.y * QG(0, g);
            zs = __fmaf_rn(p1.y, QG(1, g), zs);
            zs = __fmaf_rn(p2.y, QG(2, g), zs);
            zs = __fmaf_rn(p3.y, QG(3, g), zs);
            const float spd = __builtin_amdgcn_sqrtf(__fmaf_rn(xp, xp, zp * zp));
            acc = __fmaf_rn(slo_half(zs), spd, acc);
        }
    }

    // Boundary rows 0, 1, nknots, nknots+1 — exact polyline, global threads 0..3.
    const int gtid = blockIdx.x * BLOCK + threadIdx.x;
    if (gtid < 4) {
        const int row = (gtid < 2) ? gtid : nknots + (gtid - 2);
        acc += row_contrib((const float*)y2, row, nknots);
    }

    // Block reduce: wave shuffle + cross-wave LDS.
    #pragma unroll
    for (int off = 32; off > 0; off >>= 1) acc += __shfl_down(acc, off, 64);
    __shared__ float wsum[BLOCK / 64];
    if ((threadIdx.x & 63) == 0) wsum[threadIdx.x >> 6] = acc;
    __syncthreads();
    if (threadIdx.x == 0) {
        float t = 0.0f;
        #pragma unroll
        for (int w = 0; w < BLOCK / 64; ++w) t += wsum[w];
        partial[blockIdx.x] = t;
    }

    cg::this_grid().sync();

    // Block 0 folds the 1024 partials.
    if (blockIdx.x == 0) {
        float a = 0.0f;
        #pragma unroll
        for (int k = 0; k < GRID / BLOCK; ++k)
            a += partial[k * BLOCK + threadIdx.x];
        #pragma unroll
        for (int off = 32; off > 0; off >>= 1) a += __shfl_down(a, off, 64);
        __shared__ float fsum[BLOCK / 64];
        if ((threadIdx.x & 63) == 0) fsum[threadIdx.x >> 6] = a;
        __syncthreads();
        if (threadIdx.x == 0) {
            float t = 0.0f;
            #pragma unroll
            for (int w = 0; w < BLOCK / 64; ++w) t += fsum[w];
            out[0] = t;
        }
    }
}

} // namespace

extern "C" void kernel_launch(void* const* d_in, const int* in_sizes, int n_in,
                              void* d_out, int out_size, void* d_ws, size_t ws_size,
                              hipStream_t stream) {
    const float2* y2 = (const float2*)d_in[0];
    int nknots = in_sizes[0] / 2 - 1;
    int n_interior = nknots - 2;
    if (n_interior < 0) n_interior = 0;
    float* partial = (float*)d_ws;
    float* out = (float*)d_out;

    void* args[] = {(void*)&y2, (void*)&n_interior, (void*)&nknots,
                    (void*)&partial, (void*)&out};
    hipLaunchCooperativeKernel((const void*)raybend_coop, dim3(GRID), dim3(BLOCK),
                               args, 0, stream);
}